// Round 18
// baseline (167.775 us; speedup 1.0000x reference)
//
#include <hip/hip_runtime.h>
#include <hip/hip_bf16.h>

// GRU2 + FC, r16: grp0 slimmed to pure recurrence; ALL x-terms to grp2.
// vs r15 (161us): grp0 was pacing (~100 VALU + 8 MFMA). Now grp2 computes
// xR/xZ/xN in exact f32 from global x one step ahead -> xA[2][3][64][20];
// grp0 inits = 3 LDS vec reads, MFMA 8->6, xf-setup deleted. xhi (64KB)
// deleted -> LDS ~70KB, shorter prologue. Parity = proven xnB pattern.
// 16 waves / 4 groups / ONE barrier per step:
// grp0 w0-3:  L0 step i: whh0 MFMA(6) + act + h0 write
// grp1 w4-7:  ih1*h0(t), t=i-1 -> pP (R/Z/X partials, 6 MFMA)
// grp2 w8-11: x-terms(t=i+1) f32 (3 gates, 60 FMA) -> xA
// grp3 w12-15: hh1*h1(t-1) + pP + act -> h1, t=i-2 (6 MFMA)
// h f16 hi-only (validated 4.88e-4, R16/R17). exp2-folded activations
// (R,N x -log2e/-2log2e; Z x +log2e; validated). Layouts m89-verified:
// D col=lane&15,row=4*(lane>>4)+reg; A row=lane&15, k=kk*32+8*(lane>>4)+j.

typedef __attribute__((ext_vector_type(8))) _Float16 f16x8;
typedef __attribute__((ext_vector_type(4))) float f32x4;

#define MFMA16(a, b, c) __builtin_amdgcn_mfma_f32_16x16x32_f16(a, b, c, 0, 0, 0)

#define T_SZ 256
#define HB   72
#define NLOG2E  (-1.4426950408889634f)
#define PLOG2E  ( 1.4426950408889634f)
#define N2LOG2E (-2.8853900817779268f)

__device__ __forceinline__ void load_wfrag_hi(const float* __restrict__ W, int grow,
                                              int kbase, float scale, f16x8& hi) {
#pragma unroll
    for (int j = 0; j < 8; ++j)
        hi[j] = (_Float16)(W[grow * 64 + kbase + j] * scale);
}

__global__ __launch_bounds__(1024, 1)
void gru2_slim0(const float* __restrict__ x,
                const float* __restrict__ w_ih0, const float* __restrict__ w_hh0,
                const float* __restrict__ b_ih0, const float* __restrict__ b_hh0,
                const float* __restrict__ w_ih1, const float* __restrict__ w_hh1,
                const float* __restrict__ b_ih1, const float* __restrict__ b_hh1,
                const float* __restrict__ fc_w, const float* __restrict__ fc_b,
                float* __restrict__ out)
{
    __shared__ __align__(16) _Float16 h0hi[2][16][HB];    // 4.5 KB each
    __shared__ __align__(16) _Float16 h1hi[2][16][HB];
    __shared__ __align__(16) float    pP[2][3][64][20];   // 30.7 KB partials
    __shared__ __align__(16) float    xA[2][3][64][20];   // 30.7 KB x-terms

    const int tid  = threadIdx.x;
    const int lane = tid & 63;
    const int wave = tid >> 6;        // 0..15
    const int grp  = wave >> 2;       // 0=L0, 1=ih1, 2=x-terms, 3=hh1+act
    const int wl   = wave & 3;
    const int u    = lane & 15;
    const int kq   = lane >> 4;
    const int ug   = wl * 16 + u;     // gate-unit 0..63
    const int rbase = 4 * kq;

    for (int idx = tid; idx < 2 * 16 * HB; idx += 1024) {
        ((_Float16*)h0hi)[idx] = (_Float16)0.0f;
        ((_Float16*)h1hi)[idx] = (_Float16)0.0f;
    }
    __syncthreads();

    if (grp == 0) {
        // ======= L0 step i: whh0 MFMA(6) + act + h0 write =======
        f16x8 wR[2], wZ[2], wN[2];
#pragma unroll
        for (int kk = 0; kk < 2; ++kk) {
            const int kb = kk * 32 + 8 * kq;
            load_wfrag_hi(w_hh0, 0 * 64 + ug, kb, NLOG2E,  wR[kk]);
            load_wfrag_hi(w_hh0, 1 * 64 + ug, kb, PLOG2E,  wZ[kk]);
            load_wfrag_hi(w_hh0, 2 * 64 + ug, kb, N2LOG2E, wN[kk]);
        }
        const float bHN0 = b_hh0[128 + ug] * N2LOG2E;
        float h0_own[4] = {0.f, 0.f, 0.f, 0.f};

        // prologue: i=0 inits (exact f32 from global x)
        f32x4 proR, proZ, proX;
        {
            float wxr[5], wxz[5], wxn[5];
#pragma unroll
            for (int d = 0; d < 5; ++d) {
                wxr[d] = w_ih0[(0 * 64 + ug) * 5 + d] * NLOG2E;
                wxz[d] = w_ih0[(1 * 64 + ug) * 5 + d] * PLOG2E;
                wxn[d] = w_ih0[(128 + ug) * 5 + d] * N2LOG2E;
            }
            const float bR0  = (b_ih0[ug] + b_hh0[ug]) * NLOG2E;
            const float bZ0  = (b_ih0[64 + ug] + b_hh0[64 + ug]) * PLOG2E;
            const float bXN0 = b_ih0[128 + ug] * N2LOG2E;
#pragma unroll
            for (int r = 0; r < 4; ++r) {
                const float* xp = x + ((size_t)(blockIdx.x * 16 + rbase + r) * T_SZ) * 5;
                float vR = bR0, vZ = bZ0, vN = bXN0;
#pragma unroll
                for (int d = 0; d < 5; ++d) {
                    float x1 = xp[d];
                    vR = fmaf(wxr[d], x1, vR);
                    vZ = fmaf(wxz[d], x1, vZ);
                    vN = fmaf(wxn[d], x1, vN);
                }
                proR[r] = vR; proZ[r] = vZ; proX[r] = vN;
            }
        }

        for (int i = 0; i <= T_SZ + 1; ++i) {
            if (i < T_SZ) {
                const int pr = (i + 1) & 1, ps = i & 1;
                f16x8 ah[2];
                ah[0] = *(const f16x8*)&h0hi[pr][u][8 * kq];
                ah[1] = *(const f16x8*)&h0hi[pr][u][32 + 8 * kq];
                f32x4 aR, aZ, aNa, aNb;
                float xn0[4];
                if (i == 0) {
                    aR = proR; aZ = proZ;
#pragma unroll
                    for (int r = 0; r < 4; ++r) xn0[r] = proX[r];
                } else {
                    aR = *(const f32x4*)&xA[i & 1][0][ug][rbase];
                    aZ = *(const f32x4*)&xA[i & 1][1][ug][rbase];
                    const f32x4 q = *(const f32x4*)&xA[i & 1][2][ug][rbase];
#pragma unroll
                    for (int r = 0; r < 4; ++r) xn0[r] = q[r];
                }
#pragma unroll
                for (int r = 0; r < 4; ++r) { aNa[r] = bHN0; aNb[r] = 0.f; }
                __builtin_amdgcn_s_setprio(1);
                aNa = MFMA16(ah[0], wN[0], aNa);
                aNb = MFMA16(ah[1], wN[1], aNb);
                aR  = MFMA16(ah[0], wR[0], aR);
                aZ  = MFMA16(ah[0], wZ[0], aZ);
                aR  = MFMA16(ah[1], wR[1], aR);
                aZ  = MFMA16(ah[1], wZ[1], aZ);
                __builtin_amdgcn_s_setprio(0);
#pragma unroll
                for (int r = 0; r < 4; ++r) {
                    float ER = __builtin_amdgcn_exp2f(aR[r]);
                    float rg = __builtin_amdgcn_rcpf(1.0f + ER);
                    float w  = fmaf(rg, aNa[r] + aNb[r], xn0[r]);
                    float EN = __builtin_amdgcn_exp2f(w);
                    float n  = fmaf(2.0f, __builtin_amdgcn_rcpf(1.0f + EN), -1.0f);
                    float EZ = __builtin_amdgcn_exp2f(aZ[r]);
                    float hv = fmaf(EZ, h0_own[r], n) * __builtin_amdgcn_rcpf(1.0f + EZ);
                    h0_own[r] = hv;
                    h0hi[ps][rbase + r][ug] = (_Float16)hv;
                }
            }
            __syncthreads();
        }
    } else if (grp == 1) {
        // ==== ih1 * h0(t), t = i-1 -> pP (R/Z/X partials) ====
        f16x8 iR[2], iZ[2], iX[2];
#pragma unroll
        for (int kk = 0; kk < 2; ++kk) {
            const int kb = kk * 32 + 8 * kq;
            load_wfrag_hi(w_ih1, 0 * 64 + ug, kb, NLOG2E,  iR[kk]);
            load_wfrag_hi(w_ih1, 1 * 64 + ug, kb, PLOG2E,  iZ[kk]);
            load_wfrag_hi(w_ih1, 2 * 64 + ug, kb, N2LOG2E, iX[kk]);
        }
        const float bR1 = (b_ih1[ug] + b_hh1[ug]) * NLOG2E;
        const float bZ1 = (b_ih1[64 + ug] + b_hh1[64 + ug]) * PLOG2E;
        const float bX1 = b_ih1[128 + ug] * N2LOG2E;

        for (int i = 0; i <= T_SZ + 1; ++i) {
            if (i >= 1 && i <= T_SZ) {
                const int t = i - 1, st = t & 1;
                f16x8 ah[2];
                ah[0] = *(const f16x8*)&h0hi[st][u][8 * kq];
                ah[1] = *(const f16x8*)&h0hi[st][u][32 + 8 * kq];
                f32x4 qR = {bR1, bR1, bR1, bR1};
                f32x4 qZ = {bZ1, bZ1, bZ1, bZ1};
                f32x4 qXa = {bX1, bX1, bX1, bX1};
                f32x4 qXb = {0.f, 0.f, 0.f, 0.f};
                qR  = MFMA16(ah[0], iR[0], qR);
                qZ  = MFMA16(ah[0], iZ[0], qZ);
                qXa = MFMA16(ah[0], iX[0], qXa);
                qXb = MFMA16(ah[1], iX[1], qXb);
                qR  = MFMA16(ah[1], iR[1], qR);
                qZ  = MFMA16(ah[1], iZ[1], qZ);
#pragma unroll
                for (int r = 0; r < 4; ++r) qXa[r] += qXb[r];
                *(f32x4*)&pP[st][0][ug][rbase] = qR;
                *(f32x4*)&pP[st][1][ug][rbase] = qZ;
                *(f32x4*)&pP[st][2][ug][rbase] = qXa;
            }
            __syncthreads();
        }
    } else if (grp == 2) {
        // ==== x-terms(t=i+1), exact f32 from global x -> xA[(i+1)&1] ====
        float wxr[5], wxz[5], wxn[5];
#pragma unroll
        for (int d = 0; d < 5; ++d) {
            wxr[d] = w_ih0[(0 * 64 + ug) * 5 + d] * NLOG2E;
            wxz[d] = w_ih0[(1 * 64 + ug) * 5 + d] * PLOG2E;
            wxn[d] = w_ih0[(128 + ug) * 5 + d] * N2LOG2E;
        }
        const float bR0  = (b_ih0[ug] + b_hh0[ug]) * NLOG2E;
        const float bZ0  = (b_ih0[64 + ug] + b_hh0[64 + ug]) * PLOG2E;
        const float bXN0 = b_ih0[128 + ug] * N2LOG2E;

        for (int i = 0; i <= T_SZ + 1; ++i) {
            if (i <= T_SZ - 2) {
                f32x4 xvR, xvZ, xvN;
#pragma unroll
                for (int r = 0; r < 4; ++r) {
                    const float* xp = x + ((size_t)(blockIdx.x * 16 + rbase + r) * T_SZ + (i + 1)) * 5;
                    float vR = bR0, vZ = bZ0, vN = bXN0;
#pragma unroll
                    for (int d = 0; d < 5; ++d) {
                        float x1 = xp[d];
                        vR = fmaf(wxr[d], x1, vR);
                        vZ = fmaf(wxz[d], x1, vZ);
                        vN = fmaf(wxn[d], x1, vN);
                    }
                    xvR[r] = vR; xvZ[r] = vZ; xvN[r] = vN;
                }
                const int sl = (i + 1) & 1;
                *(f32x4*)&xA[sl][0][ug][rbase] = xvR;
                *(f32x4*)&xA[sl][1][ug][rbase] = xvZ;
                *(f32x4*)&xA[sl][2][ug][rbase] = xvN;
            }
            __syncthreads();
        }
    } else {
        // ====== hh1 * h1(t-1) + partials(t) + act -> h1, t = i-2 ======
        f16x8 hR[2], hZ[2], hN[2];
#pragma unroll
        for (int kk = 0; kk < 2; ++kk) {
            const int kb = kk * 32 + 8 * kq;
            load_wfrag_hi(w_hh1, 0 * 64 + ug, kb, NLOG2E,  hR[kk]);
            load_wfrag_hi(w_hh1, 1 * 64 + ug, kb, PLOG2E,  hZ[kk]);
            load_wfrag_hi(w_hh1, 2 * 64 + ug, kb, N2LOG2E, hN[kk]);
        }
        const float bN1 = b_hh1[128 + ug] * N2LOG2E;
        float h1_own[4] = {0.f, 0.f, 0.f, 0.f};

        for (int i = 0; i <= T_SZ + 1; ++i) {
            if (i >= 2) {
                const int t = i - 2, st = t & 1;
                f16x8 ah[2];                             // h1(t-1), slot st^1
                ah[0] = *(const f16x8*)&h1hi[st ^ 1][u][8 * kq];
                ah[1] = *(const f16x8*)&h1hi[st ^ 1][u][32 + 8 * kq];
                const f32x4 qR = *(const f32x4*)&pP[st][0][ug][rbase];
                const f32x4 qZ = *(const f32x4*)&pP[st][1][ug][rbase];
                const f32x4 qX = *(const f32x4*)&pP[st][2][ug][rbase];
                f32x4 cR = {0.f, 0.f, 0.f, 0.f};
                f32x4 cZ = {0.f, 0.f, 0.f, 0.f};
                f32x4 cNa = {bN1, bN1, bN1, bN1};
                f32x4 cNb = {0.f, 0.f, 0.f, 0.f};
                __builtin_amdgcn_s_setprio(1);
                cR  = MFMA16(ah[0], hR[0], cR);
                cZ  = MFMA16(ah[0], hZ[0], cZ);
                cNa = MFMA16(ah[0], hN[0], cNa);
                cNb = MFMA16(ah[1], hN[1], cNb);
                cR  = MFMA16(ah[1], hR[1], cR);
                cZ  = MFMA16(ah[1], hZ[1], cZ);
                __builtin_amdgcn_s_setprio(0);
#pragma unroll
                for (int r = 0; r < 4; ++r) {
                    float ER = __builtin_amdgcn_exp2f(cR[r] + qR[r]);
                    float rg = __builtin_amdgcn_rcpf(1.0f + ER);
                    float w  = fmaf(rg, cNa[r] + cNb[r], qX[r]);
                    float EN = __builtin_amdgcn_exp2f(w);
                    float n  = fmaf(2.0f, __builtin_amdgcn_rcpf(1.0f + EN), -1.0f);
                    float EZ = __builtin_amdgcn_exp2f(cZ[r] + qZ[r]);
                    float hv = fmaf(EZ, h1_own[r], n) * __builtin_amdgcn_rcpf(1.0f + EZ);
                    h1_own[r] = hv;
                    h1hi[st][rbase + r][ug] = (_Float16)hv;
                }
            }
            __syncthreads();
        }
    }

    // ---- FC epilogue: h1(255) in slot 255&1 = 1 ----
    if (tid < 16) {
        float s = fc_b[0];
#pragma unroll 1
        for (int uu = 0; uu < 64; ++uu)
            s = fmaf(fc_w[uu], (float)h1hi[1][tid][uu], s);
        out[blockIdx.x * 16 + tid] = s;
    }
}

extern "C" void kernel_launch(void* const* d_in, const int* in_sizes, int n_in,
                              void* d_out, int out_size, void* d_ws, size_t ws_size,
                              hipStream_t stream) {
    const float* x     = (const float*)d_in[0];
    const float* w_ih0 = (const float*)d_in[1];
    const float* w_hh0 = (const float*)d_in[2];
    const float* b_ih0 = (const float*)d_in[3];
    const float* b_hh0 = (const float*)d_in[4];
    const float* w_ih1 = (const float*)d_in[5];
    const float* w_hh1 = (const float*)d_in[6];
    const float* b_ih1 = (const float*)d_in[7];
    const float* b_hh1 = (const float*)d_in[8];
    const float* fc_w  = (const float*)d_in[9];
    const float* fc_b  = (const float*)d_in[10];
    float* out = (float*)d_out;

    gru2_slim0<<<dim3(256), dim3(1024), 0, stream>>>(x, w_ih0, w_hh0, b_ih0, b_hh0,
                                                     w_ih1, w_hh1, b_ih1, b_hh1,
                                                     fc_w, fc_b, out);
}

// Round 19
// 161.146 us; speedup vs baseline: 1.0411x; 1.0411x over previous
//
#include <hip/hip_runtime.h>
#include <hip/hip_bf16.h>

// GRU2 + FC, r17 = r15 verbatim (measured best: 161.3us, absmax 4.88e-4).
// R18's rebalance (x-terms to grp2) regressed to 168us: grp2 became pacing
// and grp0's inits moved from registers to post-barrier LDS reads on the
// critical path. Reverting. This is the practical floor of the 4-group
// lockstep structure: per-SIMD VALU issue ~875 cyc/step (58% busy), rest is
// chain latency + barrier skew; occupancy capped at 4 waves/SIMD.
// 16 waves / 4 groups / ONE barrier per step:
// grp0 w0-3:  L0 step i (sparse-K x-MFMA R/Z + whh0 + act + h0 write)
// grp1 w4-7:  ih1*h0(t), t=i-1 -> pP (R/Z/X partials, 6 MFMA)
// grp2 w8-11: xn(i+1) = bXN0 + x.w_N (f32, global x) -> xnB
// grp3 w12-15: hh1*h1(t-1) + pP + act -> h1, t=i-2 (6 MFMA)
// h f16 hi-only (validated); exp2-folded activations (R,N x -log2e/-2log2e;
// Z x +log2e; validated). Layouts m89-verified: D col=lane&15,
// row=4*(lane>>4)+reg; A row=lane&15, k=kk*32+8*(lane>>4)+j.

typedef __attribute__((ext_vector_type(8))) _Float16 f16x8;
typedef __attribute__((ext_vector_type(4))) float f32x4;

#define MFMA16(a, b, c) __builtin_amdgcn_mfma_f32_16x16x32_f16(a, b, c, 0, 0, 0)

#define T_SZ 256
#define HB   72
#define NLOG2E  (-1.4426950408889634f)
#define PLOG2E  ( 1.4426950408889634f)
#define N2LOG2E (-2.8853900817779268f)

__device__ __forceinline__ void load_wfrag_hi(const float* __restrict__ W, int grow,
                                              int kbase, float scale, f16x8& hi) {
#pragma unroll
    for (int j = 0; j < 8; ++j)
        hi[j] = (_Float16)(W[grow * 64 + kbase + j] * scale);
}

__global__ __launch_bounds__(1024, 1)
void gru2_16w(const float* __restrict__ x,
              const float* __restrict__ w_ih0, const float* __restrict__ w_hh0,
              const float* __restrict__ b_ih0, const float* __restrict__ b_hh0,
              const float* __restrict__ w_ih1, const float* __restrict__ w_hh1,
              const float* __restrict__ b_ih1, const float* __restrict__ b_hh1,
              const float* __restrict__ fc_w, const float* __restrict__ fc_b,
              float* __restrict__ out)
{
    __shared__ __align__(16) _Float16 xhi[T_SZ][16][8];   // 64 KB (x hi f16)
    __shared__ __align__(16) _Float16 h0hi[2][16][HB];    // 4.5 KB each
    __shared__ __align__(16) _Float16 h1hi[2][16][HB];
    __shared__ __align__(16) float    pP[2][3][64][20];   // 30.7 KB partials
    __shared__ __align__(16) float    xnB[2][64][20];     // 10.2 KB xn(t)

    const int tid  = threadIdx.x;
    const int lane = tid & 63;
    const int wave = tid >> 6;        // 0..15
    const int grp  = wave >> 2;       // 0=L0, 1=ih1, 2=xn, 3=hh1+act
    const int wl   = wave & 3;
    const int u    = lane & 15;
    const int kq   = lane >> 4;
    const int ug   = wl * 16 + u;     // gate-unit 0..63
    const int rbase = 4 * kq;

    // ---- stage xhi (f16, zero-padded cols 5..7); zero h arrays ----
    {
        const float* xsrc = x + (size_t)blockIdx.x * (16 * 1280);
        for (int idx = tid; idx < 16 * 1280; idx += 1024) {
            int row = idx / 1280;
            int rem = idx - row * 1280;
            int t   = rem / 5;
            int d   = rem - t * 5;
            xhi[t][row][d] = (_Float16)xsrc[idx];
        }
        for (int idx = tid; idx < T_SZ * 16; idx += 1024) {
            int t = idx >> 4, row = idx & 15;
            xhi[t][row][5] = (_Float16)0.0f;
            xhi[t][row][6] = (_Float16)0.0f;
            xhi[t][row][7] = (_Float16)0.0f;
        }
        for (int idx = tid; idx < 2 * 16 * HB; idx += 1024) {
            ((_Float16*)h0hi)[idx] = (_Float16)0.0f;
            ((_Float16*)h1hi)[idx] = (_Float16)0.0f;
        }
    }
    __syncthreads();

    if (grp == 0) {
        // ======= L0 step i: x-MFMA(R,Z) + whh0 MFMA + act + h0 write =======
        f16x8 wR[2], wZ[2], wN[2];
#pragma unroll
        for (int kk = 0; kk < 2; ++kk) {
            const int kb = kk * 32 + 8 * kq;
            load_wfrag_hi(w_hh0, 0 * 64 + ug, kb, NLOG2E,  wR[kk]);
            load_wfrag_hi(w_hh0, 1 * 64 + ug, kb, PLOG2E,  wZ[kk]);
            load_wfrag_hi(w_hh0, 2 * 64 + ug, kb, N2LOG2E, wN[kk]);
        }
        f16x8 bxR, bxZ;
#pragma unroll
        for (int j = 0; j < 8; ++j) { bxR[j] = (_Float16)0.0f; bxZ[j] = (_Float16)0.0f; }
        if (kq == 0) {
#pragma unroll
            for (int j = 0; j < 5; ++j) {
                bxR[j] = (_Float16)(w_ih0[(0 * 64 + ug) * 5 + j] * NLOG2E);
                bxZ[j] = (_Float16)(w_ih0[(1 * 64 + ug) * 5 + j] * PLOG2E);
            }
        }
        const float bR0  = (b_ih0[ug] + b_hh0[ug]) * NLOG2E;
        const float bZ0  = (b_ih0[64 + ug] + b_hh0[64 + ug]) * PLOG2E;
        const float bXN0 = b_ih0[128 + ug] * N2LOG2E;
        const float bHN0 = b_hh0[128 + ug] * N2LOG2E;
        float h0_own[4] = {0.f, 0.f, 0.f, 0.f};

        float xn_pro[4];
        {
            float wxn[5];
#pragma unroll
            for (int d = 0; d < 5; ++d) wxn[d] = w_ih0[(128 + ug) * 5 + d] * N2LOG2E;
#pragma unroll
            for (int r = 0; r < 4; ++r) {
                const float* xp = x + ((size_t)(blockIdx.x * 16 + rbase + r) * T_SZ) * 5;
                float vN = bXN0;
#pragma unroll
                for (int d = 0; d < 5; ++d) vN = fmaf(wxn[d], xp[d], vN);
                xn_pro[r] = vN;
            }
        }

        for (int i = 0; i <= T_SZ + 1; ++i) {
            if (i < T_SZ) {
                const int pr = (i + 1) & 1, ps = i & 1;
                f16x8 xf;
#pragma unroll
                for (int j = 0; j < 8; ++j) xf[j] = (_Float16)0.0f;
                if (kq == 0) xf = *(const f16x8*)&xhi[i][u][0];
                f16x8 ah[2];
                ah[0] = *(const f16x8*)&h0hi[pr][u][8 * kq];
                ah[1] = *(const f16x8*)&h0hi[pr][u][32 + 8 * kq];
                f32x4 aR  = {bR0, bR0, bR0, bR0};
                f32x4 aZ  = {bZ0, bZ0, bZ0, bZ0};
                f32x4 aNa = {bHN0, bHN0, bHN0, bHN0};
                f32x4 aNb = {0.f, 0.f, 0.f, 0.f};
                __builtin_amdgcn_s_setprio(1);
                aR  = MFMA16(xf, bxR, aR);
                aZ  = MFMA16(xf, bxZ, aZ);
                aNa = MFMA16(ah[0], wN[0], aNa);
                aNb = MFMA16(ah[1], wN[1], aNb);
                aR  = MFMA16(ah[0], wR[0], aR);
                aZ  = MFMA16(ah[0], wZ[0], aZ);
                aR  = MFMA16(ah[1], wR[1], aR);
                aZ  = MFMA16(ah[1], wZ[1], aZ);
                __builtin_amdgcn_s_setprio(0);
                float xn0[4];
                if (i == 0) {
#pragma unroll
                    for (int r = 0; r < 4; ++r) xn0[r] = xn_pro[r];
                } else {
                    const f32x4 q = *(const f32x4*)&xnB[i & 1][ug][rbase];
#pragma unroll
                    for (int r = 0; r < 4; ++r) xn0[r] = q[r];
                }
#pragma unroll
                for (int r = 0; r < 4; ++r) {
                    float ER = __builtin_amdgcn_exp2f(aR[r]);
                    float rg = __builtin_amdgcn_rcpf(1.0f + ER);
                    float w  = fmaf(rg, aNa[r] + aNb[r], xn0[r]);
                    float EN = __builtin_amdgcn_exp2f(w);
                    float n  = fmaf(2.0f, __builtin_amdgcn_rcpf(1.0f + EN), -1.0f);
                    float EZ = __builtin_amdgcn_exp2f(aZ[r]);
                    float hv = fmaf(EZ, h0_own[r], n) * __builtin_amdgcn_rcpf(1.0f + EZ);
                    h0_own[r] = hv;
                    h0hi[ps][rbase + r][ug] = (_Float16)hv;
                }
            }
            __syncthreads();
        }
    } else if (grp == 1) {
        // ==== ih1 * h0(t), t = i-1 -> pP (R/Z/X partials) ====
        f16x8 iR[2], iZ[2], iX[2];
#pragma unroll
        for (int kk = 0; kk < 2; ++kk) {
            const int kb = kk * 32 + 8 * kq;
            load_wfrag_hi(w_ih1, 0 * 64 + ug, kb, NLOG2E,  iR[kk]);
            load_wfrag_hi(w_ih1, 1 * 64 + ug, kb, PLOG2E,  iZ[kk]);
            load_wfrag_hi(w_ih1, 2 * 64 + ug, kb, N2LOG2E, iX[kk]);
        }
        const float bR1 = (b_ih1[ug] + b_hh1[ug]) * NLOG2E;
        const float bZ1 = (b_ih1[64 + ug] + b_hh1[64 + ug]) * PLOG2E;
        const float bX1 = b_ih1[128 + ug] * N2LOG2E;

        for (int i = 0; i <= T_SZ + 1; ++i) {
            if (i >= 1 && i <= T_SZ) {
                const int t = i - 1, st = t & 1;
                f16x8 ah[2];
                ah[0] = *(const f16x8*)&h0hi[st][u][8 * kq];
                ah[1] = *(const f16x8*)&h0hi[st][u][32 + 8 * kq];
                f32x4 qR = {bR1, bR1, bR1, bR1};
                f32x4 qZ = {bZ1, bZ1, bZ1, bZ1};
                f32x4 qXa = {bX1, bX1, bX1, bX1};
                f32x4 qXb = {0.f, 0.f, 0.f, 0.f};
                qR  = MFMA16(ah[0], iR[0], qR);
                qZ  = MFMA16(ah[0], iZ[0], qZ);
                qXa = MFMA16(ah[0], iX[0], qXa);
                qXb = MFMA16(ah[1], iX[1], qXb);
                qR  = MFMA16(ah[1], iR[1], qR);
                qZ  = MFMA16(ah[1], iZ[1], qZ);
#pragma unroll
                for (int r = 0; r < 4; ++r) qXa[r] += qXb[r];
                *(f32x4*)&pP[st][0][ug][rbase] = qR;
                *(f32x4*)&pP[st][1][ug][rbase] = qZ;
                *(f32x4*)&pP[st][2][ug][rbase] = qXa;
            }
            __syncthreads();
        }
    } else if (grp == 2) {
        // ==== xn(i+1) = bXN0 + x(t=i+1).w_N  (f32, global x) -> xnB ====
        float wxn[5];
#pragma unroll
        for (int d = 0; d < 5; ++d) wxn[d] = w_ih0[(128 + ug) * 5 + d] * N2LOG2E;
        const float bXN0 = b_ih0[128 + ug] * N2LOG2E;

        for (int i = 0; i <= T_SZ + 1; ++i) {
            if (i <= T_SZ - 2) {
                f32x4 xnv;
#pragma unroll
                for (int r = 0; r < 4; ++r) {
                    const float* xp = x + ((size_t)(blockIdx.x * 16 + rbase + r) * T_SZ + (i + 1)) * 5;
                    float vN = bXN0;
#pragma unroll
                    for (int d = 0; d < 5; ++d) vN = fmaf(wxn[d], xp[d], vN);
                    xnv[r] = vN;
                }
                *(f32x4*)&xnB[(i + 1) & 1][ug][rbase] = xnv;
            }
            __syncthreads();
        }
    } else {
        // ====== hh1 * h1(t-1) + partials(t) + act -> h1, t = i-2 ======
        f16x8 hR[2], hZ[2], hN[2];
#pragma unroll
        for (int kk = 0; kk < 2; ++kk) {
            const int kb = kk * 32 + 8 * kq;
            load_wfrag_hi(w_hh1, 0 * 64 + ug, kb, NLOG2E,  hR[kk]);
            load_wfrag_hi(w_hh1, 1 * 64 + ug, kb, PLOG2E,  hZ[kk]);
            load_wfrag_hi(w_hh1, 2 * 64 + ug, kb, N2LOG2E, hN[kk]);
        }
        const float bN1 = b_hh1[128 + ug] * N2LOG2E;
        float h1_own[4] = {0.f, 0.f, 0.f, 0.f};

        for (int i = 0; i <= T_SZ + 1; ++i) {
            if (i >= 2) {
                const int t = i - 2, st = t & 1;
                f16x8 ah[2];                             // h1(t-1), slot st^1
                ah[0] = *(const f16x8*)&h1hi[st ^ 1][u][8 * kq];
                ah[1] = *(const f16x8*)&h1hi[st ^ 1][u][32 + 8 * kq];
                const f32x4 qR = *(const f32x4*)&pP[st][0][ug][rbase];
                const f32x4 qZ = *(const f32x4*)&pP[st][1][ug][rbase];
                const f32x4 qX = *(const f32x4*)&pP[st][2][ug][rbase];
                f32x4 cR = {0.f, 0.f, 0.f, 0.f};
                f32x4 cZ = {0.f, 0.f, 0.f, 0.f};
                f32x4 cNa = {bN1, bN1, bN1, bN1};
                f32x4 cNb = {0.f, 0.f, 0.f, 0.f};
                __builtin_amdgcn_s_setprio(1);
                cR  = MFMA16(ah[0], hR[0], cR);
                cZ  = MFMA16(ah[0], hZ[0], cZ);
                cNa = MFMA16(ah[0], hN[0], cNa);
                cNb = MFMA16(ah[1], hN[1], cNb);
                cR  = MFMA16(ah[1], hR[1], cR);
                cZ  = MFMA16(ah[1], hZ[1], cZ);
                __builtin_amdgcn_s_setprio(0);
#pragma unroll
                for (int r = 0; r < 4; ++r) {
                    float ER = __builtin_amdgcn_exp2f(cR[r] + qR[r]);
                    float rg = __builtin_amdgcn_rcpf(1.0f + ER);
                    float w  = fmaf(rg, cNa[r] + cNb[r], qX[r]);
                    float EN = __builtin_amdgcn_exp2f(w);
                    float n  = fmaf(2.0f, __builtin_amdgcn_rcpf(1.0f + EN), -1.0f);
                    float EZ = __builtin_amdgcn_exp2f(cZ[r] + qZ[r]);
                    float hv = fmaf(EZ, h1_own[r], n) * __builtin_amdgcn_rcpf(1.0f + EZ);
                    h1_own[r] = hv;
                    h1hi[st][rbase + r][ug] = (_Float16)hv;
                }
            }
            __syncthreads();
        }
    }

    // ---- FC epilogue: h1(255) in slot 255&1 = 1 ----
    if (tid < 16) {
        float s = fc_b[0];
#pragma unroll 1
        for (int uu = 0; uu < 64; ++uu)
            s = fmaf(fc_w[uu], (float)h1hi[1][tid][uu], s);
        out[blockIdx.x * 16 + tid] = s;
    }
}

extern "C" void kernel_launch(void* const* d_in, const int* in_sizes, int n_in,
                              void* d_out, int out_size, void* d_ws, size_t ws_size,
                              hipStream_t stream) {
    const float* x     = (const float*)d_in[0];
    const float* w_ih0 = (const float*)d_in[1];
    const float* w_hh0 = (const float*)d_in[2];
    const float* b_ih0 = (const float*)d_in[3];
    const float* b_hh0 = (const float*)d_in[4];
    const float* w_ih1 = (const float*)d_in[5];
    const float* w_hh1 = (const float*)d_in[6];
    const float* b_ih1 = (const float*)d_in[7];
    const float* b_hh1 = (const float*)d_in[8];
    const float* fc_w  = (const float*)d_in[9];
    const float* fc_b  = (const float*)d_in[10];
    float* out = (float*)d_out;

    gru2_16w<<<dim3(256), dim3(1024), 0, stream>>>(x, w_ih0, w_hh0, b_ih0, b_hh0,
                                                   w_ih1, w_hh1, b_ih1, b_hh1,
                                                   fc_w, fc_b, out);
}